// Round 8
// baseline (4855.867 us; speedup 1.0000x reference)
//
#include <hip/hip_runtime.h>

typedef short v8s __attribute__((ext_vector_type(8)));
typedef float v4f __attribute__((ext_vector_type(4)));
typedef unsigned short ushort_t;
typedef unsigned int uint_t;

// ---------- helpers ----------
__device__ inline ushort_t f2bf(float f) {
    union { float f; uint_t u; } v; v.f = f;
    uint_t r = v.u + 0x7FFFu + ((v.u >> 16) & 1u);   // RNE
    return (ushort_t)(r >> 16);
}
__device__ inline float bf2f(ushort_t h) {
    union { uint_t u; float f; } v; v.u = ((uint_t)h) << 16;
    return v.f;
}
__device__ inline float sigf(float x) { return 1.f / (1.f + __expf(-x)); }
__device__ inline float tanh_f(float x) {
    float e = __expf(-2.f * x);
    return (1.f - e) / (1.f + e);
}

// ---------- lengths ----------
__global__ void k_lens(const int* __restrict__ tc, const int* __restrict__ uh,
                       int* lens_s, int* lens_h, int* lens_c) {
    int t = blockIdx.x * 256 + threadIdx.x;
    if (t < 640) {
        int c = 0;
        for (int s = 0; s < 50; ++s) c += (tc[t * 53 + 3 + s] != 0);
        lens_s[t] = c;
    } else if (t < 2240) {
        int r = t - 640; int c = 0;
        for (int s = 0; s < 50; ++s) c += (uh[r * 50 + s] != 0);
        lens_h[r] = c;
    } else if (t < 2272) {
        int b = t - 2240; int c = 0;
        for (int tt = 0; tt < 20; ++tt) c += (tc[(b * 20 + tt) * 53 + 3] != 0);
        lens_c[b] = c;
    }
}

// ---------- sort by length descending (brute-force rank, multi-block) ----------
__global__ void k_sort(const int* __restrict__ lens, int n,
                       int* __restrict__ perm, int* __restrict__ slen) {
    int i = blockIdx.x * 256 + threadIdx.x;
    if (i >= n) return;
    int li = lens[i]; int r = 0;
    for (int j = 0; j < n; ++j) {
        int lj = lens[j];
        r += (lj > li) || (lj == li && j < i);
    }
    perm[r] = i; slen[r] = li;
}

// ---------- pack A weights, gate-interleaved: n' = d*4 + gate ----------
// K layout: [0..299]=Wih, [300]=bih+bhh, [301..319]=0, [320..469]=Whh, [470..479]=0
__global__ void k_packA(const float* __restrict__ Wih, const float* __restrict__ Whh,
                        const float* __restrict__ bih, const float* __restrict__ bhh,
                        ushort_t* __restrict__ pack) {
    int job = blockIdx.x; int lane = threadIdx.x;
    int set = job / 570; int rem = job % 570; int tile = rem / 15; int kc = rem % 15;
    int np = tile * 16 + (lane & 15);
    int g = np & 3, d = np >> 2;
    int orig = g * 150 + d;
    int kbase = kc * 32 + (lane >> 4) * 8;
    ushort_t v[8];
#pragma unroll
    for (int j = 0; j < 8; ++j) {
        int k = kbase + j; float f = 0.f;
        if (np < 600) {
            if (k < 300) f = Wih[((size_t)set * 600 + orig) * 300 + k];
            else if (k == 300) f = bih[set * 600 + orig] + bhh[set * 600 + orig];
            else if (k >= 320 && k < 470) f = Whh[((size_t)set * 600 + orig) * 150 + (k - 320)];
        }
        v[j] = f2bf(f);
    }
    uint4 u;
    u.x = (uint_t)v[0] | ((uint_t)v[1] << 16);
    u.y = (uint_t)v[2] | ((uint_t)v[3] << 16);
    u.z = (uint_t)v[4] | ((uint_t)v[5] << 16);
    u.w = (uint_t)v[6] | ((uint_t)v[7] << 16);
    *(uint4*)(pack + ((size_t)job * 64 + lane) * 8) = u;
}

// ---------- pack C weights (Din=303, bias at k=303) ----------
__global__ void k_packC(const float* __restrict__ Wih, const float* __restrict__ Whh,
                        const float* __restrict__ bih, const float* __restrict__ bhh,
                        ushort_t* __restrict__ pack) {
    int job = blockIdx.x; int lane = threadIdx.x;
    int dir = job / 570; int rem = job % 570; int tile = rem / 15; int kc = rem % 15;
    int np = tile * 16 + (lane & 15);
    int g = np & 3, d = np >> 2;
    int orig = g * 150 + d;
    int kbase = kc * 32 + (lane >> 4) * 8;
    ushort_t v[8];
#pragma unroll
    for (int j = 0; j < 8; ++j) {
        int k = kbase + j; float f = 0.f;
        if (np < 600) {
            if (k < 303) f = Wih[((size_t)dir * 600 + orig) * 303 + k];
            else if (k == 303) f = bih[dir * 600 + orig] + bhh[dir * 600 + orig];
            else if (k >= 320 && k < 470) f = Whh[((size_t)dir * 600 + orig) * 150 + (k - 320)];
        }
        v[j] = f2bf(f);
    }
    uint4 u;
    u.x = (uint_t)v[0] | ((uint_t)v[1] << 16);
    u.y = (uint_t)v[2] | ((uint_t)v[3] << 16);
    u.z = (uint_t)v[4] | ((uint_t)v[5] << 16);
    u.w = (uint_t)v[6] | ((uint_t)v[7] << 16);
    *(uint4*)(pack + ((size_t)job * 64 + lane) * 8) = u;
}

// =====================================================================
// FUSED chain kernel v2: x-projection + recurrence in ONE MFMA pass.
// Register-budget fix vs R7: E rows staged in LDS per step (A-fragments
// read via ds_read_b128), single wc[15] weight buffer (no ping-pong).
// Live set ~235 VGPR -> no scratch spill. LDS = 21.5+17.4+40.6 = 79.5 KB.
// 170 blocks x 256 threads (4 waves). Wave w: rows (w>>1)*32..+31,
// tn = (w&1)*19 + j, j<19.
// =====================================================================
__launch_bounds__(256, 1)
__global__ void k_main(const int* __restrict__ tcg, const int* __restrict__ uhg,
                       const float* __restrict__ E,
                       const int* __restrict__ perm_s, const int* __restrict__ slen_s,
                       const int* __restrict__ perm_h, const int* __restrict__ hlen_s,
                       const ushort_t* __restrict__ packA,
                       float* __restrict__ srep, float* __restrict__ reps) {
    const int bid = blockIdx.x;
    const int tid = threadIdx.x;
    const int lane = tid & 63, w = tid >> 6, q = lane >> 4, l16 = lane & 15;
    const int u = w >> 1;          // m-half: rows u*32 .. u*32+31
    const int h19 = (w & 1) * 19;  // tn-base

    __shared__ ushort_t H[64][168];
    __shared__ __align__(16) float Gp[4][16][68];
    __shared__ __align__(16) ushort_t Elds[65][312];   // 64 rows + OOB guard row

    // ---- role decode ----
    int r_pos0, r_windex, r_dir, isS;
    const int* r_lenv; const int* r_permv;
    float* r_outp;
    if (bid < 20) {
        int grp = bid / 10; r_dir = grp; r_windex = grp; r_pos0 = (bid % 10) * 64;
        r_lenv = slen_s; r_permv = perm_s; r_outp = srep; isS = 1;
    } else {
        int gh = (bid - 20) / 25; r_windex = gh; r_dir = gh & 1;
        r_pos0 = ((bid - 20) % 25) * 64;
        r_lenv = hlen_s; r_permv = perm_h;
        r_outp = reps + (size_t)(gh >> 1) * 1600 * 300; isS = 0;
    }
    for (int i = tid; i < 64 * 84; i += 256) ((uint_t*)H)[i] = 0u;

    // ---- per-ROW staging metadata (row = tid&63, quarter = tid>>6) ----
    const int srow = tid & 63, sqtr = tid >> 6;
    const int lenrow = r_lenv[r_pos0 + srow];
    {
        int origrow = r_permv[r_pos0 + srow];
        (void)origrow;
    }
    const int* tokrow;
    {
        int origrow = r_permv[r_pos0 + srow];
        tokrow = isS ? (tcg + (size_t)origrow * 53 + 3) : (uhg + (size_t)origrow * 50);
    }

    // per-lane m-group lens for gate masking
    int lenm[2];
#pragma unroll
    for (int mg = 0; mg < 2; ++mg)
        lenm[mg] = r_lenv[r_pos0 + u * 32 + mg * 16 + l16];

    float cst[19][2];
#pragma unroll
    for (int j = 0; j < 19; ++j)
#pragma unroll
        for (int i = 0; i < 2; ++i) cst[j][i] = 0.f;

    const int blockmax = r_lenv[r_pos0];
    const ushort_t* wslot = packA + (size_t)r_windex * 570 * 512;

    // constant tail cols of Elds: 300 = 1.0 bias multiplier, 301..311 = 0
    if (tid < 64) {
        Elds[tid][300] = 0x3F80;
#pragma unroll
        for (int cc = 301; cc < 312; ++cc) Elds[tid][cc] = 0;
    }

    for (int t = 0; t < blockmax; ++t) {
        __syncthreads();   // prev-step H writes + Elds reads done (or init visible)

        // ---- phase 1: ah <- H(prev);  stage Elds(t) ----
        v8s ah[2][5];
#pragma unroll
        for (int mg = 0; mg < 2; ++mg)
#pragma unroll
            for (int kc = 0; kc < 5; ++kc)
                ah[mg][kc] = *(const v8s*)&H[u * 32 + mg * 16 + l16][kc * 32 + q * 8];
        {
            int tau = r_dir ? (lenrow - 1 - t) : t;
            tau = tau < 0 ? 0 : (tau > 49 ? 49 : tau);
            int tok = tokrow[tau];
            const v4f* Er = (const v4f*)(E + (size_t)tok * 300);
            uint_t* erow = (uint_t*)&Elds[srow][0];
#pragma unroll
            for (int i = 0; i < 19; ++i) {
                int k4 = sqtr * 19 + i;
                if (k4 < 75) {
                    v4f f = __builtin_nontemporal_load(Er + k4);
                    uint_t lo = (uint_t)f2bf(f[0]) | ((uint_t)f2bf(f[1]) << 16);
                    uint_t hi = (uint_t)f2bf(f[2]) | ((uint_t)f2bf(f[3]) << 16);
                    erow[k4 * 2]     = lo;
                    erow[k4 * 2 + 1] = hi;
                }
            }
        }
        __syncthreads();   // ah in regs, Elds(t) ready, H writable

        // ---- phase 2: 19 fused GEMM+gate bodies ----
#pragma unroll
        for (int j = 0; j < 19; ++j) {
            int tn = h19 + j;
            const ushort_t* wp = wslot + (size_t)tn * 15 * 512 + lane * 8;
            v8s wc[15];
#pragma unroll
            for (int kc = 0; kc < 15; ++kc) wc[kc] = *(const v8s*)(wp + (size_t)kc * 512);

            v4f acc[2];
#pragma unroll
            for (int mg = 0; mg < 2; ++mg) acc[mg] = (v4f){0.f, 0.f, 0.f, 0.f};
#pragma unroll
            for (int kc = 0; kc < 10; ++kc)
#pragma unroll
                for (int mg = 0; mg < 2; ++mg) {
                    v8s af = *(const v8s*)&Elds[u * 32 + mg * 16 + l16][kc * 32 + q * 8];
                    acc[mg] = __builtin_amdgcn_mfma_f32_16x16x32_bf16(af, wc[kc], acc[mg], 0, 0, 0);
                }
#pragma unroll
            for (int kc = 0; kc < 5; ++kc)
#pragma unroll
                for (int mg = 0; mg < 2; ++mg)
                    acc[mg] = __builtin_amdgcn_mfma_f32_16x16x32_bf16(ah[mg][kc], wc[10 + kc], acc[mg], 0, 0, 0);
#pragma unroll
            for (int mg = 0; mg < 2; ++mg)
                *(v4f*)&Gp[w][l16][mg * 16 + q * 4] = acc[mg];
            int d = 4 * tn + q;
#pragma unroll
            for (int i = 0; i < 2; ++i) {
                int mloc = l16 + 16 * i;
                if (t < lenm[i]) {
                    float gi = Gp[w][q * 4 + 0][mloc];
                    float gf = Gp[w][q * 4 + 1][mloc];
                    float gg = Gp[w][q * 4 + 2][mloc];
                    float go = Gp[w][q * 4 + 3][mloc];
                    float cn = sigf(gf) * cst[j][i] + sigf(gi) * tanh_f(gg);
                    cst[j][i] = cn;
                    if (d < 150) H[u * 32 + mloc][d] = f2bf(sigf(go) * tanh_f(cn));
                }
            }
        }
    }
    __syncthreads();   // final H writes visible

    // ---- final outputs ----
    {
        int m = tid >> 2, dc = tid & 3;
        int orig = r_permv[r_pos0 + m];
#pragma unroll
        for (int k = 0; k < 38; ++k) {
            int d = dc + 4 * k;
            if (d < 150) r_outp[(size_t)orig * 300 + r_dir * 150 + d] = bf2f(H[m][d]);
        }
    }
}

// ---------- C-LSTM x-projection GEMM (split over tn via blockIdx.z) ----------
// rows per dir: R = b*20 + t (consumption step t); A source te = dir? clen-1-t : t
// gxc layout: [dir][t][tn][b<32][l16<16] ushort
__launch_bounds__(256, 1)
__global__ void k_gxc(const float* __restrict__ srep, const int* __restrict__ tcg,
                      const int* __restrict__ lens_c, const ushort_t* __restrict__ packC,
                      ushort_t* __restrict__ gxc) {
    const int dir = blockIdx.y;
    const int R0 = blockIdx.x * 256;
    const int tnbase = blockIdx.z * 2;
    const int tid = threadIdx.x, lane = tid & 63, w = tid >> 6, q = lane >> 4, l16 = lane & 15;

    v8s a[4][10];
#pragma unroll
    for (int mtg = 0; mtg < 4; ++mtg) {
        int R = R0 + w * 64 + mtg * 16 + l16;
        R = R < 639 ? R : 639;
        int b = R / 20, t = R % 20;
        int clen = lens_c[b];
        int te = dir ? (clen - 1 - t) : t;
        te = te < 0 ? 0 : (te > 19 ? 19 : te);
        const float* sr = srep + (size_t)(b * 20 + te) * 300;
        const int* ft = tcg + (size_t)(b * 20 + te) * 53;
#pragma unroll
        for (int kc = 0; kc < 9; ++kc) {
            int k0 = kc * 32 + q * 8;
            float4 f0 = *(const float4*)(sr + k0);
            float4 f1 = *(const float4*)(sr + k0 + 4);
            v8s r;
            r[0] = (short)f2bf(f0.x); r[1] = (short)f2bf(f0.y);
            r[2] = (short)f2bf(f0.z); r[3] = (short)f2bf(f0.w);
            r[4] = (short)f2bf(f1.x); r[5] = (short)f2bf(f1.y);
            r[6] = (short)f2bf(f1.z); r[7] = (short)f2bf(f1.w);
            a[mtg][kc] = r;
        }
        {   // kc=9: k = 288+q*8+j; 300..302 = feats, 303 = 1.0
            v8s r = (v8s){0,0,0,0,0,0,0,0};
            if (q == 0) {
                float4 f0 = *(const float4*)(sr + 288);
                float4 f1 = *(const float4*)(sr + 292);
                r[0] = (short)f2bf(f0.x); r[1] = (short)f2bf(f0.y);
                r[2] = (short)f2bf(f0.z); r[3] = (short)f2bf(f0.w);
                r[4] = (short)f2bf(f1.x); r[5] = (short)f2bf(f1.y);
                r[6] = (short)f2bf(f1.z); r[7] = (short)f2bf(f1.w);
            } else if (q == 1) {
                float4 f0 = *(const float4*)(sr + 296);
                r[0] = (short)f2bf(f0.x); r[1] = (short)f2bf(f0.y);
                r[2] = (short)f2bf(f0.z); r[3] = (short)f2bf(f0.w);
                r[4] = (short)f2bf((float)ft[0]);
                r[5] = (short)f2bf((float)ft[1]);
                r[6] = (short)f2bf((float)ft[2]);
                r[7] = (short)0x3F80;
            }
            a[mtg][9] = r;
        }
    }
    const ushort_t* W = packC + (size_t)dir * 570 * 512;
    v8s bA[10];
    auto loadB = [&](v8s* dst, int tn) {
        const ushort_t* p = W + (size_t)tn * 15 * 512 + lane * 8;
#pragma unroll
        for (int kc = 0; kc < 10; ++kc) dst[kc] = *(const v8s*)(p + (size_t)kc * 512);
    };
    auto compute = [&](int tn, v8s* b) {
        v4f acc[4];
#pragma unroll
        for (int mtg = 0; mtg < 4; ++mtg) acc[mtg] = (v4f){0.f, 0.f, 0.f, 0.f};
#pragma unroll
        for (int kc = 0; kc < 10; ++kc)
#pragma unroll
            for (int mtg = 0; mtg < 4; ++mtg)
                acc[mtg] = __builtin_amdgcn_mfma_f32_16x16x32_bf16(a[mtg][kc], b[kc], acc[mtg], 0, 0, 0);
#pragma unroll
        for (int mtg = 0; mtg < 4; ++mtg)
#pragma unroll
            for (int r = 0; r < 4; ++r) {
                int R = R0 + w * 64 + mtg * 16 + q * 4 + r;
                if (R < 640) {
                    int b = R / 20, t = R % 20;
                    gxc[(((size_t)(dir * 20 + t) * 38 + tn) << 9) + b * 16 + l16] = f2bf(acc[mtg][r]);
                }
            }
    };
    for (int tn = tnbase; tn < tnbase + 2; ++tn) {
        loadB(bA, tn);
        compute(tn, bA);
    }
}

// ---------- conversation-level recurrence: register Whh, M=32 ----------
__launch_bounds__(256, 1)
__global__ void k_rec_c(const ushort_t* __restrict__ gxc, const int* __restrict__ lens_c,
                        const ushort_t* __restrict__ packC, float* __restrict__ out) {
    const int dir = blockIdx.x;
    const int tid = threadIdx.x, lane = tid & 63, w = tid >> 6, q = lane >> 4, l16 = lane & 15;

    __shared__ ushort_t H[32][168];
    __shared__ __align__(16) float Gp[4][16][68];
    __shared__ int lensl[32];
    __shared__ int mxs;

    if (tid < 32) lensl[tid] = lens_c[tid];
    for (int i = tid; i < 32 * 84; i += 256) ((uint_t*)H)[i] = 0u;
    __syncthreads();
    if (tid == 0) {
        int mx = 0;
        for (int i = 0; i < 32; ++i) mx = max(mx, lensl[i]);
        mxs = mx;
    }
    __syncthreads();
    const int maxlen = mxs;
    int len2[2];
#pragma unroll
    for (int i = 0; i < 2; ++i) len2[i] = lensl[i * 16 + l16];

    v8s wb[10][5];
#pragma unroll
    for (int j = 0; j < 10; ++j) {
        int tn = w + 4 * j; int tnc = tn > 37 ? 37 : tn;
        const ushort_t* wp = packC + (size_t)dir * 570 * 512 + (size_t)tnc * 15 * 512 + lane * 8;
#pragma unroll
        for (int kc = 0; kc < 5; ++kc) wb[j][kc] = *(const v8s*)(wp + (size_t)(10 + kc) * 512);
    }
    float cst[10][2];
#pragma unroll
    for (int j = 0; j < 10; ++j)
#pragma unroll
        for (int i = 0; i < 2; ++i) cst[j][i] = 0.f;

    for (int t = 0; t < maxlen; ++t) {
        __syncthreads();
        v8s ah[2][5];
#pragma unroll
        for (int mtg = 0; mtg < 2; ++mtg)
#pragma unroll
            for (int kc = 0; kc < 5; ++kc)
                ah[mtg][kc] = *(const v8s*)&H[mtg * 16 + l16][kc * 32 + q * 8];
        __syncthreads();
#pragma unroll
        for (int j = 0; j < 10; ++j) {
            int tn = w + 4 * j;
            if (tn < 38) {
                v4f acc[2];
#pragma unroll
                for (int mtg = 0; mtg < 2; ++mtg) acc[mtg] = (v4f){0.f, 0.f, 0.f, 0.f};
#pragma unroll
                for (int kc = 0; kc < 5; ++kc)
#pragma unroll
                    for (int mtg = 0; mtg < 2; ++mtg)
                        acc[mtg] = __builtin_amdgcn_mfma_f32_16x16x32_bf16(ah[mtg][kc], wb[j][kc], acc[mtg], 0, 0, 0);
#pragma unroll
                for (int mtg = 0; mtg < 2; ++mtg)
                    *(v4f*)&Gp[w][l16][mtg * 16 + q * 4] = acc[mtg];
                int d = 4 * tn + q;
                const ushort_t* gbase = gxc + (((size_t)(dir * 20 + t) * 38 + tn) << 9) + q * 4;
#pragma unroll
                for (int i = 0; i < 2; ++i) {
                    int m = l16 + 16 * i;
                    if (t < len2[i]) {
                        ushort4 gv = *(const ushort4*)(gbase + m * 16);
                        float gi = bf2f(gv.x) + Gp[w][q * 4 + 0][m];
                        float gf = bf2f(gv.y) + Gp[w][q * 4 + 1][m];
                        float gg = bf2f(gv.z) + Gp[w][q * 4 + 2][m];
                        float go = bf2f(gv.w) + Gp[w][q * 4 + 3][m];
                        float cn = sigf(gf) * cst[j][i] + sigf(gi) * tanh_f(gg);
                        cst[j][i] = cn;
                        if (d < 150) H[m][d] = f2bf(sigf(go) * tanh_f(cn));
                    }
                }
            }
        }
    }
    __syncthreads();
    {
        int m = tid >> 3;
#pragma unroll
        for (int k = 0; k < 19; ++k) {
            int d = (tid & 7) + 8 * k;
            if (d < 150) out[(size_t)m * 300 + dir * 150 + d] = bf2f(H[m][d]);
        }
    }
}

// ---------- attention hops + output ----------
__global__ void k_attn(const float* __restrict__ reps, const float* __restrict__ u_in,
                       const float* __restrict__ Wout, const float* __restrict__ bout,
                       float* __restrict__ out) {
    const int b = blockIdx.x;
    const int tid = threadIdx.x;
    const int wave = tid >> 6, lane = tid & 63;
    __shared__ float u_l[300];
    __shared__ float dots[64];
    __shared__ float red[4];
    for (int d = tid; d < 300; d += 256) u_l[d] = u_in[b * 300 + d];
    __syncthreads();
    for (int hop = 0; hop < 2; ++hop) {
        const float* R0 = reps + ((size_t)hop * 1600 + b * 50) * 300;
        for (int n = wave; n < 50; n += 4) {
            float p = 0.f;
            for (int d = lane; d < 300; d += 64) p += R0[(size_t)n * 300 + d] * u_l[d];
            for (int off = 32; off > 0; off >>= 1) p += __shfl_down(p, off);
            if (lane == 0) dots[n] = p;
        }
        __syncthreads();
        if (tid < 64) {
            float x = (lane < 50) ? dots[lane] : -3.4e38f;
            float mx = x;
            for (int off = 32; off > 0; off >>= 1) mx = fmaxf(mx, __shfl_down(mx, off));
            mx = __shfl(mx, 0);
            float e = (lane < 50) ? __expf(x - mx) : 0.f;
            float s = e;
            for (int off = 32; off > 0; off >>= 1) s += __shfl_down(s, off);
            s = __shfl(s, 0);
            if (lane < 50) dots[lane] = e / s;
        }
        __syncthreads();
        const float* R1 = reps + ((size_t)(hop + 1) * 1600 + b * 50) * 300;
        for (int d = tid; d < 300; d += 256) {
            float s = 0.f;
            for (int n = 0; n < 50; ++n) s += dots[n] * R1[(size_t)n * 300 + d];
            u_l[d] += s;
        }
        __syncthreads();
    }
    float acc = 0.f;
    for (int d = tid; d < 300; d += 256) acc += u_l[d] * Wout[d];
    for (int off = 32; off > 0; off >>= 1) acc += __shfl_down(acc, off);
    if (lane == 0) red[wave] = acc;
    __syncthreads();
    if (tid == 0) {
        float s = red[0] + red[1] + red[2] + red[3] + bout[0];
        out[b] = 1.f / (1.f + __expf(-s));
    }
}

// ---------- launch ----------
extern "C" void kernel_launch(void* const* d_in, const int* in_sizes, int n_in,
                              void* d_out, int out_size, void* d_ws, size_t ws_size,
                              hipStream_t stream) {
    (void)in_sizes; (void)n_in; (void)out_size; (void)ws_size;
    const int*   tc   = (const int*)d_in[0];
    const int*   uh   = (const int*)d_in[1];
    const float* E    = (const float*)d_in[2];
    const float* AWih = (const float*)d_in[3];
    const float* AWhh = (const float*)d_in[4];
    const float* Abih = (const float*)d_in[5];
    const float* Abhh = (const float*)d_in[6];
    const float* CWih = (const float*)d_in[7];
    const float* CWhh = (const float*)d_in[8];
    const float* Cbih = (const float*)d_in[9];
    const float* Cbhh = (const float*)d_in[10];
    const float* Wout = (const float*)d_in[11];
    const float* bout = (const float*)d_in[12];
    float* out = (float*)d_out;

    char* ws = (char*)d_ws;
    size_t off = 0;
    auto take = [&](size_t bytes) -> char* {
        char* p = ws + off;
        off = (off + bytes + 255) & ~(size_t)255;
        return p;
    };
    int* lens_s = (int*)take(640 * 4);
    int* lens_h = (int*)take(1600 * 4);
    int* lens_c = (int*)take(32 * 4);
    int* perm_s = (int*)take(640 * 4);
    int* slen_sorted = (int*)take(640 * 4);
    int* perm_h = (int*)take(1600 * 4);
    int* hlen_sorted = (int*)take(1600 * 4);
    ushort_t* packA = (ushort_t*)take((size_t)6 * 570 * 512 * 2);
    ushort_t* packC = (ushort_t*)take((size_t)2 * 570 * 512 * 2);
    float* srep = (float*)take((size_t)640 * 300 * 4);
    float* reps = (float*)take((size_t)3 * 1600 * 300 * 4);
    float* ubuf = (float*)take((size_t)32 * 300 * 4);
    ushort_t* gxc = (ushort_t*)take((size_t)2 * 20 * 38 * 1024);

    k_lens<<<9, 256, 0, stream>>>(tc, uh, lens_s, lens_h, lens_c);
    k_sort<<<3, 256, 0, stream>>>(lens_s, 640, perm_s, slen_sorted);
    k_sort<<<7, 256, 0, stream>>>(lens_h, 1600, perm_h, hlen_sorted);
    k_packA<<<3420, 64, 0, stream>>>(AWih, AWhh, Abih, Abhh, packA);
    k_packC<<<1140, 64, 0, stream>>>(CWih, CWhh, Cbih, Cbhh, packC);

    k_main<<<170, 256, 0, stream>>>(tc, uh, E,
                                    perm_s, slen_sorted, perm_h, hlen_sorted,
                                    packA, srep, reps);

    k_gxc<<<dim3(3, 2, 19), 256, 0, stream>>>(srep, tc, lens_c, packC, gxc);
    k_rec_c<<<2, 256, 0, stream>>>(gxc, lens_c, packC, ubuf);
    k_attn<<<32, 256, 0, stream>>>(reps, ubuf, Wout, bout, out);
}

// Round 9
// 2419.230 us; speedup vs baseline: 2.0072x; 2.0072x over previous
//
#include <hip/hip_runtime.h>

typedef short v8s __attribute__((ext_vector_type(8)));
typedef float v4f __attribute__((ext_vector_type(4)));
typedef unsigned short ushort_t;
typedef unsigned int uint_t;

// ---------- helpers ----------
__device__ inline ushort_t f2bf(float f) {
    union { float f; uint_t u; } v; v.f = f;
    uint_t r = v.u + 0x7FFFu + ((v.u >> 16) & 1u);   // RNE
    return (ushort_t)(r >> 16);
}
__device__ inline float bf2f(ushort_t h) {
    union { uint_t u; float f; } v; v.u = ((uint_t)h) << 16;
    return v.f;
}
__device__ inline float sigf(float x) { return 1.f / (1.f + __expf(-x)); }
__device__ inline float tanh_f(float x) {
    float e = __expf(-2.f * x);
    return (1.f - e) / (1.f + e);
}

// ---------- lengths ----------
__global__ void k_lens(const int* __restrict__ tc, const int* __restrict__ uh,
                       int* lens_s, int* lens_h, int* lens_c) {
    int t = blockIdx.x * 256 + threadIdx.x;
    if (t < 640) {
        int c = 0;
        for (int s = 0; s < 50; ++s) c += (tc[t * 53 + 3 + s] != 0);
        lens_s[t] = c;
    } else if (t < 2240) {
        int r = t - 640; int c = 0;
        for (int s = 0; s < 50; ++s) c += (uh[r * 50 + s] != 0);
        lens_h[r] = c;
    } else if (t < 2272) {
        int b = t - 2240; int c = 0;
        for (int tt = 0; tt < 20; ++tt) c += (tc[(b * 20 + tt) * 53 + 3] != 0);
        lens_c[b] = c;
    }
}

// ---------- sort by length descending (brute-force rank, multi-block) ----------
__global__ void k_sort(const int* __restrict__ lens, int n,
                       int* __restrict__ perm, int* __restrict__ slen) {
    int i = blockIdx.x * 256 + threadIdx.x;
    if (i >= n) return;
    int li = lens[i]; int r = 0;
    for (int j = 0; j < n; ++j) {
        int lj = lens[j];
        r += (lj > li) || (lj == li && j < i);
    }
    perm[r] = i; slen[r] = li;
}

// ---------- pack A weights, gate-interleaved: n' = d*4 + gate ----------
// K layout: [0..299]=Wih, [300]=bih+bhh, [301..319]=0, [320..469]=Whh, [470..479]=0
__global__ void k_packA(const float* __restrict__ Wih, const float* __restrict__ Whh,
                        const float* __restrict__ bih, const float* __restrict__ bhh,
                        ushort_t* __restrict__ pack) {
    int job = blockIdx.x; int lane = threadIdx.x;
    int set = job / 570; int rem = job % 570; int tile = rem / 15; int kc = rem % 15;
    int np = tile * 16 + (lane & 15);
    int g = np & 3, d = np >> 2;
    int orig = g * 150 + d;
    int kbase = kc * 32 + (lane >> 4) * 8;
    ushort_t v[8];
#pragma unroll
    for (int j = 0; j < 8; ++j) {
        int k = kbase + j; float f = 0.f;
        if (np < 600) {
            if (k < 300) f = Wih[((size_t)set * 600 + orig) * 300 + k];
            else if (k == 300) f = bih[set * 600 + orig] + bhh[set * 600 + orig];
            else if (k >= 320 && k < 470) f = Whh[((size_t)set * 600 + orig) * 150 + (k - 320)];
        }
        v[j] = f2bf(f);
    }
    uint4 u;
    u.x = (uint_t)v[0] | ((uint_t)v[1] << 16);
    u.y = (uint_t)v[2] | ((uint_t)v[3] << 16);
    u.z = (uint_t)v[4] | ((uint_t)v[5] << 16);
    u.w = (uint_t)v[6] | ((uint_t)v[7] << 16);
    *(uint4*)(pack + ((size_t)job * 64 + lane) * 8) = u;
}

// ---------- pack C weights (Din=303, bias at k=303) ----------
__global__ void k_packC(const float* __restrict__ Wih, const float* __restrict__ Whh,
                        const float* __restrict__ bih, const float* __restrict__ bhh,
                        ushort_t* __restrict__ pack) {
    int job = blockIdx.x; int lane = threadIdx.x;
    int dir = job / 570; int rem = job % 570; int tile = rem / 15; int kc = rem % 15;
    int np = tile * 16 + (lane & 15);
    int g = np & 3, d = np >> 2;
    int orig = g * 150 + d;
    int kbase = kc * 32 + (lane >> 4) * 8;
    ushort_t v[8];
#pragma unroll
    for (int j = 0; j < 8; ++j) {
        int k = kbase + j; float f = 0.f;
        if (np < 600) {
            if (k < 303) f = Wih[((size_t)dir * 600 + orig) * 303 + k];
            else if (k == 303) f = bih[dir * 600 + orig] + bhh[dir * 600 + orig];
            else if (k >= 320 && k < 470) f = Whh[((size_t)dir * 600 + orig) * 150 + (k - 320)];
        }
        v[j] = f2bf(f);
    }
    uint4 u;
    u.x = (uint_t)v[0] | ((uint_t)v[1] << 16);
    u.y = (uint_t)v[2] | ((uint_t)v[3] << 16);
    u.z = (uint_t)v[4] | ((uint_t)v[5] << 16);
    u.w = (uint_t)v[6] | ((uint_t)v[7] << 16);
    *(uint4*)(pack + ((size_t)job * 64 + lane) * 8) = u;
}

// =====================================================================
// FUSED chain kernel v3: x-projection + recurrence, weights delivered
// through LDS via global_load_lds (double-buffered, shared by m-half
// wave pairs). A-fragments register-resident per step (a[2][10]).
// Live set ~205 VGPR (no spill). LDS = 21.5+17.4+40.6+61.4 = 137.6 KB.
// 170 blocks x 256 threads (4 waves). Wave w: m-half u=w>>1 (rows
// u*32..+31), tn-half hh=w&1 (tn = hh*19 + j, j<19).
// =====================================================================
__launch_bounds__(256, 1)
__global__ void k_main(const int* __restrict__ tcg, const int* __restrict__ uhg,
                       const float* __restrict__ E,
                       const int* __restrict__ perm_s, const int* __restrict__ slen_s,
                       const int* __restrict__ perm_h, const int* __restrict__ hlen_s,
                       const ushort_t* __restrict__ packA,
                       float* __restrict__ srep, float* __restrict__ reps) {
    const int bid = blockIdx.x;
    const int tid = threadIdx.x;
    const int lane = tid & 63, w = tid >> 6, q = lane >> 4, l16 = lane & 15;
    const int u = w >> 1;          // m-half
    const int hh = w & 1;          // tn-half

    __shared__ ushort_t H[64][168];
    __shared__ __align__(16) float Gp[4][16][68];
    __shared__ __align__(16) ushort_t Elds[65][312];          // 64 rows + guard
    __shared__ __align__(16) ushort_t Wlds[2][2][15][512];    // dbuf x tn-half x kc x 1KB

    // ---- role decode ----
    int r_pos0, r_windex, r_dir, isS;
    const int* r_lenv; const int* r_permv;
    float* r_outp;
    if (bid < 20) {
        int grp = bid / 10; r_dir = grp; r_windex = grp; r_pos0 = (bid % 10) * 64;
        r_lenv = slen_s; r_permv = perm_s; r_outp = srep; isS = 1;
    } else {
        int gh = (bid - 20) / 25; r_windex = gh; r_dir = gh & 1;
        r_pos0 = ((bid - 20) % 25) * 64;
        r_lenv = hlen_s; r_permv = perm_h;
        r_outp = reps + (size_t)(gh >> 1) * 1600 * 300; isS = 0;
    }
    for (int i = tid; i < 64 * 84; i += 256) ((uint_t*)H)[i] = 0u;

    // staging metadata: row = tid&63, quarter = tid>>6
    const int srow = tid & 63, sqtr = tid >> 6;
    const int lenrow = r_lenv[r_pos0 + srow];
    const int* tokrow;
    {
        int origrow = r_permv[r_pos0 + srow];
        tokrow = isS ? (tcg + (size_t)origrow * 53 + 3) : (uhg + (size_t)origrow * 50);
    }
    int lenm[2];
#pragma unroll
    for (int mg = 0; mg < 2; ++mg)
        lenm[mg] = r_lenv[r_pos0 + u * 32 + mg * 16 + l16];

    float cst[19][2];
#pragma unroll
    for (int j = 0; j < 19; ++j)
#pragma unroll
        for (int i = 0; i < 2; ++i) cst[j][i] = 0.f;

    const int blockmax = r_lenv[r_pos0];
    const ushort_t* wslot = packA + (size_t)r_windex * 570 * 512;

    // stage weights for jbody jn into buffer pn: 30 1KB tiles, wave w takes
    // tiles w, w+4, ... ; global_load_lds: per-lane 16B -> ldsbase+lane*16.
    auto stageW = [&](int jn, int pn) {
        for (int tile = w; tile < 30; tile += 4) {
            int th = tile / 15, kc = tile % 15;
            int tn = th * 19 + jn;
            const ushort_t* src = wslot + ((size_t)tn * 15 + kc) * 512 + lane * 8;
            ushort_t* dst = &Wlds[pn][th][kc][0];
            __builtin_amdgcn_global_load_lds(
                (const __attribute__((address_space(1))) uint_t*)src,
                (__attribute__((address_space(3))) uint_t*)dst, 16, 0, 0);
        }
    };

    // constant tail cols of Elds: 300 = 1.0 bias multiplier, 301..311 = 0
    if (tid < 64) {
        Elds[tid][300] = 0x3F80;
#pragma unroll
        for (int cc = 301; cc < 312; ++cc) Elds[tid][cc] = 0;
    }
    stageW(0, 0);          // prologue: j=0 weights -> buf0
    __syncthreads();       // H zero + Elds tails + buf0 stage drained

    int p = 0;             // step-entry weight-buffer parity
    for (int t = 0; t < blockmax; ++t) {
        // H(prev) visible (prologue barrier or last jbody barrier)
        v8s ah[2][5];
#pragma unroll
        for (int mg = 0; mg < 2; ++mg)
#pragma unroll
            for (int kc = 0; kc < 5; ++kc)
                ah[mg][kc] = *(const v8s*)&H[u * 32 + mg * 16 + l16][kc * 32 + q * 8];
        {   // stage E rows for step t (plain loads: let L2/L3 serve re-reads)
            int tau = r_dir ? (lenrow - 1 - t) : t;
            tau = tau < 0 ? 0 : (tau > 49 ? 49 : tau);
            int tok = tokrow[tau];
            const v4f* Er = (const v4f*)(E + (size_t)tok * 300);
            uint_t* erow = (uint_t*)&Elds[srow][0];
#pragma unroll
            for (int i = 0; i < 19; ++i) {
                int k4 = sqtr * 19 + i;
                if (k4 < 75) {
                    v4f f = Er[k4];
                    erow[k4 * 2]     = (uint_t)f2bf(f[0]) | ((uint_t)f2bf(f[1]) << 16);
                    erow[k4 * 2 + 1] = (uint_t)f2bf(f[2]) | ((uint_t)f2bf(f[3]) << 16);
                }
            }
        }
        __syncthreads();   // Elds(t) ready; ah in regs (H writable); Wlds[p] ready

        // A-fragments register-resident for the whole step
        v8s a[2][10];
#pragma unroll
        for (int mg = 0; mg < 2; ++mg)
#pragma unroll
            for (int kc = 0; kc < 10; ++kc)
                a[mg][kc] = *(const v8s*)&Elds[u * 32 + mg * 16 + l16][kc * 32 + q * 8];

#pragma unroll
        for (int j = 0; j < 19; ++j) {
            const int pj = p ^ (j & 1);
            const int jn = (j < 18) ? j + 1 : 0;   // j=18 pre-stages next step's j=0
            stageW(jn, pj ^ 1);                    // issue early, drains at barrier

            int tn = hh * 19 + j;
            v4f acc[2];
#pragma unroll
            for (int mg = 0; mg < 2; ++mg) acc[mg] = (v4f){0.f, 0.f, 0.f, 0.f};
#pragma unroll
            for (int kc = 0; kc < 10; ++kc) {
                v8s wc = *(const v8s*)&Wlds[pj][hh][kc][lane * 8];
#pragma unroll
                for (int mg = 0; mg < 2; ++mg)
                    acc[mg] = __builtin_amdgcn_mfma_f32_16x16x32_bf16(a[mg][kc], wc, acc[mg], 0, 0, 0);
            }
#pragma unroll
            for (int kc = 0; kc < 5; ++kc) {
                v8s wc = *(const v8s*)&Wlds[pj][hh][10 + kc][lane * 8];
#pragma unroll
                for (int mg = 0; mg < 2; ++mg)
                    acc[mg] = __builtin_amdgcn_mfma_f32_16x16x32_bf16(ah[mg][kc], wc, acc[mg], 0, 0, 0);
            }
#pragma unroll
            for (int mg = 0; mg < 2; ++mg)
                *(v4f*)&Gp[w][l16][mg * 16 + q * 4] = acc[mg];
            int d = 4 * tn + q;
#pragma unroll
            for (int i = 0; i < 2; ++i) {
                int mloc = l16 + 16 * i;
                if (t < lenm[i]) {
                    float gi = Gp[w][q * 4 + 0][mloc];
                    float gf = Gp[w][q * 4 + 1][mloc];
                    float gg = Gp[w][q * 4 + 2][mloc];
                    float go = Gp[w][q * 4 + 3][mloc];
                    float cn = sigf(gf) * cst[j][i] + sigf(gi) * tanh_f(gg);
                    cst[j][i] = cn;
                    if (d < 150) H[u * 32 + mloc][d] = f2bf(sigf(go) * tanh_f(cn));
                }
            }
            __syncthreads();   // drains stage vmcnt; Wlds[pj] reads done; H writes visible
        }
        p ^= 1;   // 19 jbodies flip parity once
    }

    // ---- final outputs ----
    {
        int m = tid >> 2, dc = tid & 3;
        int orig = r_permv[r_pos0 + m];
#pragma unroll
        for (int k = 0; k < 38; ++k) {
            int d = dc + 4 * k;
            if (d < 150) r_outp[(size_t)orig * 300 + r_dir * 150 + d] = bf2f(H[m][d]);
        }
    }
}

// ---------- C-LSTM x-projection GEMM (split over tn via blockIdx.z) ----------
// rows per dir: R = b*20 + t (consumption step t); A source te = dir? clen-1-t : t
// gxc layout: [dir][t][tn][b<32][l16<16] ushort
__launch_bounds__(256, 1)
__global__ void k_gxc(const float* __restrict__ srep, const int* __restrict__ tcg,
                      const int* __restrict__ lens_c, const ushort_t* __restrict__ packC,
                      ushort_t* __restrict__ gxc) {
    const int dir = blockIdx.y;
    const int R0 = blockIdx.x * 256;
    const int tnbase = blockIdx.z * 2;
    const int tid = threadIdx.x, lane = tid & 63, w = tid >> 6, q = lane >> 4, l16 = lane & 15;

    v8s a[4][10];
#pragma unroll
    for (int mtg = 0; mtg < 4; ++mtg) {
        int R = R0 + w * 64 + mtg * 16 + l16;
        R = R < 639 ? R : 639;
        int b = R / 20, t = R % 20;
        int clen = lens_c[b];
        int te = dir ? (clen - 1 - t) : t;
        te = te < 0 ? 0 : (te > 19 ? 19 : te);
        const float* sr = srep + (size_t)(b * 20 + te) * 300;
        const int* ft = tcg + (size_t)(b * 20 + te) * 53;
#pragma unroll
        for (int kc = 0; kc < 9; ++kc) {
            int k0 = kc * 32 + q * 8;
            float4 f0 = *(const float4*)(sr + k0);
            float4 f1 = *(const float4*)(sr + k0 + 4);
            v8s r;
            r[0] = (short)f2bf(f0.x); r[1] = (short)f2bf(f0.y);
            r[2] = (short)f2bf(f0.z); r[3] = (short)f2bf(f0.w);
            r[4] = (short)f2bf(f1.x); r[5] = (short)f2bf(f1.y);
            r[6] = (short)f2bf(f1.z); r[7] = (short)f2bf(f1.w);
            a[mtg][kc] = r;
        }
        {   // kc=9: k = 288+q*8+j; 300..302 = feats, 303 = 1.0
            v8s r = (v8s){0,0,0,0,0,0,0,0};
            if (q == 0) {
                float4 f0 = *(const float4*)(sr + 288);
                float4 f1 = *(const float4*)(sr + 292);
                r[0] = (short)f2bf(f0.x); r[1] = (short)f2bf(f0.y);
                r[2] = (short)f2bf(f0.z); r[3] = (short)f2bf(f0.w);
                r[4] = (short)f2bf(f1.x); r[5] = (short)f2bf(f1.y);
                r[6] = (short)f2bf(f1.z); r[7] = (short)f2bf(f1.w);
            } else if (q == 1) {
                float4 f0 = *(const float4*)(sr + 296);
                r[0] = (short)f2bf(f0.x); r[1] = (short)f2bf(f0.y);
                r[2] = (short)f2bf(f0.z); r[3] = (short)f2bf(f0.w);
                r[4] = (short)f2bf((float)ft[0]);
                r[5] = (short)f2bf((float)ft[1]);
                r[6] = (short)f2bf((float)ft[2]);
                r[7] = (short)0x3F80;
            }
            a[mtg][9] = r;
        }
    }
    const ushort_t* W = packC + (size_t)dir * 570 * 512;
    v8s bA[10];
    auto loadB = [&](v8s* dst, int tn) {
        const ushort_t* p = W + (size_t)tn * 15 * 512 + lane * 8;
#pragma unroll
        for (int kc = 0; kc < 10; ++kc) dst[kc] = *(const v8s*)(p + (size_t)kc * 512);
    };
    auto compute = [&](int tn, v8s* b) {
        v4f acc[4];
#pragma unroll
        for (int mtg = 0; mtg < 4; ++mtg) acc[mtg] = (v4f){0.f, 0.f, 0.f, 0.f};
#pragma unroll
        for (int kc = 0; kc < 10; ++kc)
#pragma unroll
            for (int mtg = 0; mtg < 4; ++mtg)
                acc[mtg] = __builtin_amdgcn_mfma_f32_16x16x32_bf16(a[mtg][kc], b[kc], acc[mtg], 0, 0, 0);
#pragma unroll
        for (int mtg = 0; mtg < 4; ++mtg)
#pragma unroll
            for (int r = 0; r < 4; ++r) {
                int R = R0 + w * 64 + mtg * 16 + q * 4 + r;
                if (R < 640) {
                    int b = R / 20, t = R % 20;
                    gxc[(((size_t)(dir * 20 + t) * 38 + tn) << 9) + b * 16 + l16] = f2bf(acc[mtg][r]);
                }
            }
    };
    for (int tn = tnbase; tn < tnbase + 2; ++tn) {
        loadB(bA, tn);
        compute(tn, bA);
    }
}

// ---------- conversation-level recurrence: register Whh, M=32 ----------
__launch_bounds__(256, 1)
__global__ void k_rec_c(const ushort_t* __restrict__ gxc, const int* __restrict__ lens_c,
                        const ushort_t* __restrict__ packC, float* __restrict__ out) {
    const int dir = blockIdx.x;
    const int tid = threadIdx.x, lane = tid & 63, w = tid >> 6, q = lane >> 4, l16 = lane & 15;

    __shared__ ushort_t H[32][168];
    __shared__ __align__(16) float Gp[4][16][68];
    __shared__ int lensl[32];
    __shared__ int mxs;

    if (tid < 32) lensl[tid] = lens_c[tid];
    for (int i = tid; i < 32 * 84; i += 256) ((uint_t*)H)[i] = 0u;
    __syncthreads();
    if (tid == 0) {
        int mx = 0;
        for (int i = 0; i < 32; ++i) mx = max(mx, lensl[i]);
        mxs = mx;
    }
    __syncthreads();
    const int maxlen = mxs;
    int len2[2];
#pragma unroll
    for (int i = 0; i < 2; ++i) len2[i] = lensl[i * 16 + l16];

    v8s wb[10][5];
#pragma unroll
    for (int j = 0; j < 10; ++j) {
        int tn = w + 4 * j; int tnc = tn > 37 ? 37 : tn;
        const ushort_t* wp = packC + (size_t)dir * 570 * 512 + (size_t)tnc * 15 * 512 + lane * 8;
#pragma unroll
        for (int kc = 0; kc < 5; ++kc) wb[j][kc] = *(const v8s*)(wp + (size_t)(10 + kc) * 512);
    }
    float cst[10][2];
#pragma unroll
    for (int j = 0; j < 10; ++j)
#pragma unroll
        for (int i = 0; i < 2; ++i) cst[j][i] = 0.f;

    for (int t = 0; t < maxlen; ++t) {
        __syncthreads();
        v8s ah[2][5];
#pragma unroll
        for (int mtg = 0; mtg < 2; ++mtg)
#pragma unroll
            for (int kc = 0; kc < 5; ++kc)
                ah[mtg][kc] = *(const v8s*)&H[mtg * 16 + l16][kc * 32 + q * 8];
        __syncthreads();
#pragma unroll
        for (int j = 0; j < 10; ++j) {
            int tn = w + 4 * j;
            if (tn < 38) {
                v4f acc[2];
#pragma unroll
                for (int mtg = 0; mtg < 2; ++mtg) acc[mtg] = (v4f){0.f, 0.f, 0.f, 0.f};
#pragma unroll
                for (int kc = 0; kc < 5; ++kc)
#pragma unroll
                    for (int mtg = 0; mtg < 2; ++mtg)
                        acc[mtg] = __builtin_amdgcn_mfma_f32_16x16x32_bf16(ah[mtg][kc], wb[j][kc], acc[mtg], 0, 0, 0);
#pragma unroll
                for (int mtg = 0; mtg < 2; ++mtg)
                    *(v4f*)&Gp[w][l16][mtg * 16 + q * 4] = acc[mtg];
                int d = 4 * tn + q;
                const ushort_t* gbase = gxc + (((size_t)(dir * 20 + t) * 38 + tn) << 9) + q * 4;
#pragma unroll
                for (int i = 0; i < 2; ++i) {
                    int m = l16 + 16 * i;
                    if (t < len2[i]) {
                        ushort4 gv = *(const ushort4*)(gbase + m * 16);
                        float gi = bf2f(gv.x) + Gp[w][q * 4 + 0][m];
                        float gf = bf2f(gv.y) + Gp[w][q * 4 + 1][m];
                        float gg = bf2f(gv.z) + Gp[w][q * 4 + 2][m];
                        float go = bf2f(gv.w) + Gp[w][q * 4 + 3][m];
                        float cn = sigf(gf) * cst[j][i] + sigf(gi) * tanh_f(gg);
                        cst[j][i] = cn;
                        if (d < 150) H[m][d] = f2bf(sigf(go) * tanh_f(cn));
                    }
                }
            }
        }
    }
    __syncthreads();
    {
        int m = tid >> 3;
#pragma unroll
        for (int k = 0; k < 19; ++k) {
            int d = (tid & 7) + 8 * k;
            if (d < 150) out[(size_t)m * 300 + dir * 150 + d] = bf2f(H[m][d]);
        }
    }
}

// ---------- attention hops + output ----------
__global__ void k_attn(const float* __restrict__ reps, const float* __restrict__ u_in,
                       const float* __restrict__ Wout, const float* __restrict__ bout,
                       float* __restrict__ out) {
    const int b = blockIdx.x;
    const int tid = threadIdx.x;
    const int wave = tid >> 6, lane = tid & 63;
    __shared__ float u_l[300];
    __shared__ float dots[64];
    __shared__ float red[4];
    for (int d = tid; d < 300; d += 256) u_l[d] = u_in[b * 300 + d];
    __syncthreads();
    for (int hop = 0; hop < 2; ++hop) {
        const float* R0 = reps + ((size_t)hop * 1600 + b * 50) * 300;
        for (int n = wave; n < 50; n += 4) {
            float p = 0.f;
            for (int d = lane; d < 300; d += 64) p += R0[(size_t)n * 300 + d] * u_l[d];
            for (int off = 32; off > 0; off >>= 1) p += __shfl_down(p, off);
            if (lane == 0) dots[n] = p;
        }
        __syncthreads();
        if (tid < 64) {
            float x = (lane < 50) ? dots[lane] : -3.4e38f;
            float mx = x;
            for (int off = 32; off > 0; off >>= 1) mx = fmaxf(mx, __shfl_down(mx, off));
            mx = __shfl(mx, 0);
            float e = (lane < 50) ? __expf(x - mx) : 0.f;
            float s = e;
            for (int off = 32; off > 0; off >>= 1) s += __shfl_down(s, off);
            s = __shfl(s, 0);
            if (lane < 50) dots[lane] = e / s;
        }
        __syncthreads();
        const float* R1 = reps + ((size_t)(hop + 1) * 1600 + b * 50) * 300;
        for (int d = tid; d < 300; d += 256) {
            float s = 0.f;
            for (int n = 0; n < 50; ++n) s += dots[n] * R1[(size_t)n * 300 + d];
            u_l[d] += s;
        }
        __syncthreads();
    }
    float acc = 0.f;
    for (int d = tid; d < 300; d += 256) acc += u_l[d] * Wout[d];
    for (int off = 32; off > 0; off >>= 1) acc += __shfl_down(acc, off);
    if (lane == 0) red[wave] = acc;
    __syncthreads();
    if (tid == 0) {
        float s = red[0] + red[1] + red[2] + red[3] + bout[0];
        out[b] = 1.f / (1.f + __expf(-s));
    }
}

// ---------- launch ----------
extern "C" void kernel_launch(void* const* d_in, const int* in_sizes, int n_in,
                              void* d_out, int out_size, void* d_ws, size_t ws_size,
                              hipStream_t stream) {
    (void)in_sizes; (void)n_in; (void)out_size; (void)ws_size;
    const int*   tc   = (const int*)d_in[0];
    const int*   uh   = (const int*)d_in[1];
    const float* E    = (const float*)d_in[2];
    const float* AWih = (const float*)d_in[3];
    const float* AWhh = (const float*)d_in[4];
    const float* Abih = (const float*)d_in[5];
    const float* Abhh = (const float*)d_in[6];
    const float* CWih = (const float*)d_in[7];
    const float* CWhh = (const float*)d_in[8];
    const float* Cbih = (const float*)d_in[9];
    const float* Cbhh = (const float*)d_in[10];
    const float* Wout = (const float*)d_in[11];
    const float* bout = (const float*)d_in[12];
    float* out = (float*)d_out;

    char* ws = (char*)d_ws;
    size_t off = 0;
    auto take = [&](size_t bytes) -> char* {
        char* p = ws + off;
        off = (off + bytes + 255) & ~(size_t)255;
        return p;
    };
    int* lens_s = (int*)take(640 * 4);
    int* lens_h = (int*)take(1600 * 4);
    int* lens_c = (int*)take(32 * 4);
    int* perm_s = (int*)take(640 * 4);
    int* slen_sorted = (int*)take(640 * 4);
    int* perm_h = (int*)take(1600 * 4);
    int* hlen_sorted = (int*)take(1600 * 4);
    ushort_t* packA = (ushort_t*)take((size_t)6 * 570 * 512 * 2);
    ushort_t* packC = (ushort_t*)take((size_t)2 * 570 * 512 * 2);
    float* srep = (float*)take((size_t)640 * 300 * 4);
    float* reps = (float*)take((size_t)3 * 1600 * 300 * 4);
    float* ubuf = (float*)take((size_t)32 * 300 * 4);
    ushort_t* gxc = (ushort_t*)take((size_t)2 * 20 * 38 * 1024);

    k_lens<<<9, 256, 0, stream>>>(tc, uh, lens_s, lens_h, lens_c);
    k_sort<<<3, 256, 0, stream>>>(lens_s, 640, perm_s, slen_sorted);
    k_sort<<<7, 256, 0, stream>>>(lens_h, 1600, perm_h, hlen_sorted);
    k_packA<<<3420, 64, 0, stream>>>(AWih, AWhh, Abih, Abhh, packA);
    k_packC<<<1140, 64, 0, stream>>>(CWih, CWhh, Cbih, Cbhh, packC);

    k_main<<<170, 256, 0, stream>>>(tc, uh, E,
                                    perm_s, slen_sorted, perm_h, hlen_sorted,
                                    packA, srep, reps);

    k_gxc<<<dim3(3, 2, 19), 256, 0, stream>>>(srep, tc, lens_c, packC, gxc);
    k_rec_c<<<2, 256, 0, stream>>>(gxc, lens_c, packC, ubuf);
    k_attn<<<32, 256, 0, stream>>>(reps, ubuf, Wout, bout, out);
}